// Round 6
// baseline (325.190 us; speedup 1.0000x reference)
//
#include <hip/hip_runtime.h>
#include <cstdint>

#define N_SAMPLES 16384
#define DIM 2048
#define PDIM 256
#define NB 32
#define NL 100
#define NSEG (NB * NL)

typedef float floatx4 __attribute__((ext_vector_type(4)));
typedef __bf16 bf16x8 __attribute__((ext_vector_type(8)));

__device__ __forceinline__ unsigned short f32_to_bf16(float f) {
    unsigned int u = __float_as_uint(f);
    u += 0x7fffu + ((u >> 16) & 1u);   // round-to-nearest-even
    return (unsigned short)(u >> 16);
}
__device__ __forceinline__ unsigned int pack_bf16x2(float a, float b) {
    return (unsigned int)f32_to_bf16(a) | ((unsigned int)f32_to_bf16(b) << 16);
}

// ---------------------------------------------------------------------------
// prep: weights -> bf16, bias sum, seg index, zero hist
// ---------------------------------------------------------------------------
__global__ __launch_bounds__(256) void prep_kernel(
    const float* __restrict__ W1w, const float* __restrict__ W1b,
    const float* __restrict__ W2w, const float* __restrict__ W2b,
    const int* __restrict__ label, const int* __restrict__ lbatch,
    unsigned short* __restrict__ W1bf, unsigned short* __restrict__ W2bf,
    float* __restrict__ bias, int* __restrict__ seg,
    int* __restrict__ hist)
{
    int i = blockIdx.x * 256 + threadIdx.x;   // grid = PDIM*DIM threads
    W1bf[i] = f32_to_bf16(W1w[i]);
    W2bf[i] = f32_to_bf16(W2w[i]);
    if (i < PDIM) bias[i] = W1b[i] + W2b[i];
    if (i < N_SAMPLES) seg[i] = lbatch[i] * NL + label[i];
    if (i < NSEG) hist[i] = 0;
}

__global__ __launch_bounds__(256) void hist_kernel(
    const int* __restrict__ seg, int* __restrict__ hist)
{
    int i = blockIdx.x * 256 + threadIdx.x;
    atomicAdd(&hist[seg[i]], 1);
}

// ---------------------------------------------------------------------------
// scan: single WG exclusive prefix over hist[3200] -> offs[3201], cursor copy
// ---------------------------------------------------------------------------
#define SCAN_BPT 13   // 256*13 = 3328 >= 3200
__global__ __launch_bounds__(256) void scan_kernel(
    const int* __restrict__ hist, int* __restrict__ offs, int* __restrict__ cursor)
{
    __shared__ int ps[256];
    const int t = threadIdx.x;
    int local = 0;
    #pragma unroll
    for (int k = 0; k < SCAN_BPT; ++k) {
        int bin = t * SCAN_BPT + k;
        if (bin < NSEG) local += hist[bin];
    }
    ps[t] = local;
    __syncthreads();
    for (int d = 1; d < 256; d <<= 1) {
        int v = (t >= d) ? ps[t - d] : 0;
        __syncthreads();
        ps[t] += v;
        __syncthreads();
    }
    int run = ps[t] - local;   // exclusive start for this thread's range
    #pragma unroll
    for (int k = 0; k < SCAN_BPT; ++k) {
        int bin = t * SCAN_BPT + k;
        if (bin < NSEG) {
            offs[bin] = run;
            cursor[bin] = run;
            run += hist[bin];
        }
    }
    if (t == 255) offs[NSEG] = ps[255];   // = N_SAMPLES
}

__global__ __launch_bounds__(256) void scatter_kernel(
    const int* __restrict__ seg, int* __restrict__ cursor, int* __restrict__ perm)
{
    int i = blockIdx.x * 256 + threadIdx.x;
    int pos = atomicAdd(&cursor[seg[i]], 1);
    perm[pos] = i;
}

// ---------------------------------------------------------------------------
// segsum v5: wave = (segment, 512-col chunk), lane = 8 floats (2KB/wave-load,
// 1KB packed bf16 store). 4-row register batches keep 8 loads in flight while
// halving VMEM instruction count per byte vs v4.
// ---------------------------------------------------------------------------
__global__ __launch_bounds__(256) void segsum_kernel(
    const float* __restrict__ x, const int* __restrict__ perm,
    const int* __restrict__ offs,
    unsigned short* __restrict__ xb, float* __restrict__ sum_bl)
{
    const int tid = threadIdx.x;
    const int w = tid >> 6, lane = tid & 63;
    const int s = blockIdx.y * 4 + w;              // segment, 0..3199
    const int c = blockIdx.x * 512 + lane * 8;     // 8 consecutive floats/lane
    const int beg = offs[s], end = offs[s + 1];

    floatx4 sum0 = {0.f, 0.f, 0.f, 0.f};
    floatx4 sum1 = {0.f, 0.f, 0.f, 0.f};
    for (int base = beg; base < end; base += 64) {
        int p = (base + lane < end) ? perm[base + lane] : 0;
        const int n = min(end - base, 64);
        for (int j0 = 0; j0 < n; j0 += 4) {
            int rr[4];
            floatx4 v0[4], v1[4];
            #pragma unroll
            for (int j = 0; j < 4; ++j) {
                rr[j] = __shfl(p, min(j0 + j, n - 1));   // clamp: dup loads harmless
                const float* px = &x[(size_t)rr[j] * DIM + c];
                v0[j] = *(const floatx4*)px;
                v1[j] = *(const floatx4*)(px + 4);
            }
            #pragma unroll
            for (int j = 0; j < 4; ++j) {
                if (j < n - j0) {
                    sum0 += v0[j];
                    sum1 += v1[j];
                    uint4 o;
                    o.x = pack_bf16x2(v0[j][0], v0[j][1]);
                    o.y = pack_bf16x2(v0[j][2], v0[j][3]);
                    o.z = pack_bf16x2(v1[j][0], v1[j][1]);
                    o.w = pack_bf16x2(v1[j][2], v1[j][3]);
                    *(uint4*)&xb[(size_t)rr[j] * DIM + c] = o;   // 16B/lane
                }
            }
        }
    }
    *(floatx4*)&sum_bl[(size_t)s * DIM + c] = sum0;
    *(floatx4*)&sum_bl[(size_t)s * DIM + c + 4] = sum1;
}

// ---------------------------------------------------------------------------
// meanm v2 (fused sumb+meanm): WG = (batch, 256-col chunk). Single pass over
// sum_bl into LDS (100KB) computing the batch total, then LOO means -> Mb.
// Counts derived from offs (hist no longer needed here). No barriers needed:
// each thread touches only its own column.
// ---------------------------------------------------------------------------
__global__ __launch_bounds__(256) void meanm_kernel(
    const float* __restrict__ sum_bl, const int* __restrict__ offs,
    unsigned short* __restrict__ Mb)
{
    __shared__ float acc[NL][256];   // 100 KB
    const int tid = threadIdx.x;
    const int b = blockIdx.y;
    const int c = blockIdx.x * 256 + tid;

    float tot = 0.f;
    for (int l0 = 0; l0 < NL; l0 += 4) {        // 100 % 4 == 0
        float v[4];
        #pragma unroll
        for (int j = 0; j < 4; ++j)
            v[j] = sum_bl[(size_t)(b * NL + l0 + j) * DIM + c];
        #pragma unroll
        for (int j = 0; j < 4; ++j) { acc[l0 + j][tid] = v[j]; tot += v[j]; }
    }

    const int ob = offs[b * NL];
    const int cb = offs[(b + 1) * NL] - ob;     // batch count
    for (int l = 0; l < NL; ++l) {
        int dc = cb - (offs[b * NL + l + 1] - offs[b * NL + l]);
        float m = (dc > 0) ? (tot - acc[l][tid]) / (float)dc : 0.f;
        Mb[(size_t)(b * NL + l) * DIM + c] = f32_to_bf16(m);
    }
}

// ---------------------------------------------------------------------------
// GEMM: C[M,256] = A[M,K]_bf16 @ B[256,K]_bf16^T  (m97 structure)
// FUSE epilogue: += bias[col] + add[seg[row]*256 + col]
// ---------------------------------------------------------------------------
template<int BM, int BN, bool FUSE>
__global__ __launch_bounds__(256) void gemm_bt_kernel(
    const unsigned short* __restrict__ A,
    const unsigned short* __restrict__ B,
    float* __restrict__ C,
    const float* __restrict__ bias,
    const float* __restrict__ add,
    const int* __restrict__ seg,
    int K)
{
    constexpr int HBM = BM / 2, HBN = BN / 2;
    constexpr int FM = BM / 32, FN = BN / 32;
    __shared__ __align__(16) unsigned short ldsA[BM * 32];
    __shared__ __align__(16) unsigned short ldsB[BN * 32];
    const int tid = threadIdx.x;
    const int lane = tid & 63;
    const int wave = tid >> 6;
    const int wr = wave >> 1, wc = wave & 1;
    const int quad = lane >> 4, l15 = lane & 15;
    const int m0 = blockIdx.x * BM;
    const int n0 = blockIdx.y * BN;
    const int srow = lane >> 2, schunk = lane & 3;

    floatx4 acc[FM][FN];
    #pragma unroll
    for (int i = 0; i < FM; ++i)
        #pragma unroll
        for (int j = 0; j < FN; ++j) acc[i][j] = (floatx4){0.f, 0.f, 0.f, 0.f};

    const unsigned short* Abase = A + (size_t)(m0 + srow) * K + schunk * 8;
    const unsigned short* Bbase = B + (size_t)(n0 + srow) * K + schunk * 8;

    for (int kk = 0; kk < K; kk += 32) {
        __syncthreads();
        #pragma unroll
        for (int ii = 0; ii < BM / 64; ++ii) {
            const int ch = ii * 4 + wave;
            __builtin_amdgcn_global_load_lds(
                (const __attribute__((address_space(1))) void*)(Abase + (size_t)ch * 16 * K + kk),
                (__attribute__((address_space(3))) void*)&ldsA[ch * 16 * 32], 16, 0, 0);
        }
        #pragma unroll
        for (int ii = 0; ii < BN / 64; ++ii) {
            const int ch = ii * 4 + wave;
            __builtin_amdgcn_global_load_lds(
                (const __attribute__((address_space(1))) void*)(Bbase + (size_t)ch * 16 * K + kk),
                (__attribute__((address_space(3))) void*)&ldsB[ch * 16 * 32], 16, 0, 0);
        }
        __syncthreads();

        bf16x8 af[FM], bfr[FN];
        #pragma unroll
        for (int mi = 0; mi < FM; ++mi)
            af[mi] = *(const bf16x8*)&ldsA[(wr * HBM + mi * 16 + l15) * 32 + quad * 8];
        #pragma unroll
        for (int ni = 0; ni < FN; ++ni)
            bfr[ni] = *(const bf16x8*)&ldsB[(wc * HBN + ni * 16 + l15) * 32 + quad * 8];
        #pragma unroll
        for (int mi = 0; mi < FM; ++mi)
            #pragma unroll
            for (int ni = 0; ni < FN; ++ni)
                acc[mi][ni] = __builtin_amdgcn_mfma_f32_16x16x32_bf16(
                    af[mi], bfr[ni], acc[mi][ni], 0, 0, 0);
    }

    #pragma unroll
    for (int mi = 0; mi < FM; ++mi) {
        const int rbase = m0 + wr * HBM + mi * 16 + quad * 4;
        #pragma unroll
        for (int ni = 0; ni < FN; ++ni) {
            const int col = n0 + wc * HBN + ni * 16 + l15;
            float bsum = 0.f;
            if constexpr (FUSE) bsum = bias[col];
            #pragma unroll
            for (int r = 0; r < 4; ++r) {
                const int row = rbase + r;
                float v = acc[mi][ni][r];
                if constexpr (FUSE) v += bsum + add[(size_t)seg[row] * PDIM + col];
                C[(size_t)row * PDIM + col] = v;
            }
        }
    }
}

// ---------------------------------------------------------------------------
extern "C" void kernel_launch(void* const* d_in, const int* in_sizes, int n_in,
                              void* d_out, int out_size, void* d_ws, size_t ws_size,
                              hipStream_t stream)
{
    const float* x      = (const float*)d_in[0];
    const int*   label  = (const int*)d_in[1];
    const int*   lbatch = (const int*)d_in[2];
    const float* W1w    = (const float*)d_in[3];
    const float* W1b    = (const float*)d_in[4];
    const float* W2w    = (const float*)d_in[5];
    const float* W2b    = (const float*)d_in[6];
    float* out = (float*)d_out;

    char* ws = (char*)d_ws;
    size_t off = 0;
    auto alloc = [&](size_t bytes) {
        void* p = ws + off;
        off = (off + bytes + 255) & ~(size_t)255;
        return p;
    };
    unsigned short* xb   = (unsigned short*)alloc((size_t)N_SAMPLES * DIM * 2); // 67 MB
    unsigned short* Mb   = (unsigned short*)alloc((size_t)NSEG * DIM * 2);      // 13 MB
    unsigned short* W1bf = (unsigned short*)alloc((size_t)PDIM * DIM * 2);
    unsigned short* W2bf = (unsigned short*)alloc((size_t)PDIM * DIM * 2);
    float* MW2    = (float*)alloc((size_t)NSEG * PDIM * 4);                     // 3.3 MB
    float* sum_bl = (float*)alloc((size_t)NSEG * DIM * 4);                      // 26 MB
    float* bias   = (float*)alloc(PDIM * 4);
    int*   seg    = (int*)alloc(N_SAMPLES * 4);
    int*   perm   = (int*)alloc(N_SAMPLES * 4);
    int*   hist   = (int*)alloc(NSEG * 4);
    int*   offs   = (int*)alloc((NSEG + 1) * 4);
    int*   cursor = (int*)alloc(NSEG * 4);

    prep_kernel<<<PDIM * DIM / 256, 256, 0, stream>>>(
        W1w, W1b, W2w, W2b, label, lbatch, W1bf, W2bf, bias, seg, hist);

    hist_kernel<<<N_SAMPLES / 256, 256, 0, stream>>>(seg, hist);
    scan_kernel<<<1, 256, 0, stream>>>(hist, offs, cursor);
    scatter_kernel<<<N_SAMPLES / 256, 256, 0, stream>>>(seg, cursor, perm);

    segsum_kernel<<<dim3(DIM / 512, NSEG / 4), 256, 0, stream>>>(
        x, perm, offs, xb, sum_bl);

    meanm_kernel<<<dim3(DIM / 256, NB), 256, 0, stream>>>(sum_bl, offs, Mb);

    // MW2[3200,256] = M @ W2^T
    gemm_bt_kernel<64, 64, false><<<dim3(NSEG / 64, PDIM / 64), 256, 0, stream>>>(
        Mb, W2bf, MW2, nullptr, nullptr, nullptr, DIM);

    // out[16384,256] = x @ W1^T + bias + MW2[seg]  (128x64: 512 WGs = 2/CU)
    gemm_bt_kernel<128, 64, true><<<dim3(N_SAMPLES / 128, PDIM / 64), 256, 0, stream>>>(
        xb, W1bf, out, bias, MW2, seg, DIM);
}

// Round 7
// 317.729 us; speedup vs baseline: 1.0235x; 1.0235x over previous
//
#include <hip/hip_runtime.h>
#include <cstdint>

#define N_SAMPLES 16384
#define DIM 2048
#define PDIM 256
#define NB 32
#define NL 100
#define NSEG (NB * NL)

typedef float floatx4 __attribute__((ext_vector_type(4)));
typedef __bf16 bf16x8 __attribute__((ext_vector_type(8)));

__device__ __forceinline__ unsigned short f32_to_bf16(float f) {
    unsigned int u = __float_as_uint(f);
    u += 0x7fffu + ((u >> 16) & 1u);   // round-to-nearest-even
    return (unsigned short)(u >> 16);
}
__device__ __forceinline__ unsigned int pack_bf16x2(float a, float b) {
    return (unsigned int)f32_to_bf16(a) | ((unsigned int)f32_to_bf16(b) << 16);
}

// ---------------------------------------------------------------------------
// prep: weights -> bf16, bias sum, seg index, zero hist + MW2 (for split-K)
// ---------------------------------------------------------------------------
__global__ __launch_bounds__(256) void prep_kernel(
    const float* __restrict__ W1w, const float* __restrict__ W1b,
    const float* __restrict__ W2w, const float* __restrict__ W2b,
    const int* __restrict__ label, const int* __restrict__ lbatch,
    unsigned short* __restrict__ W1bf, unsigned short* __restrict__ W2bf,
    float* __restrict__ bias, int* __restrict__ seg,
    int* __restrict__ hist, float* __restrict__ MW2)
{
    int i = blockIdx.x * 256 + threadIdx.x;   // grid = PDIM*DIM threads
    W1bf[i] = f32_to_bf16(W1w[i]);
    W2bf[i] = f32_to_bf16(W2w[i]);
    if (i < PDIM) bias[i] = W1b[i] + W2b[i];
    if (i < N_SAMPLES) seg[i] = lbatch[i] * NL + label[i];
    if (i < NSEG) hist[i] = 0;
    if (i < NSEG * PDIM / 2) ((float2*)MW2)[i] = make_float2(0.f, 0.f);
}

__global__ __launch_bounds__(256) void hist_kernel(
    const int* __restrict__ seg, int* __restrict__ hist)
{
    int i = blockIdx.x * 256 + threadIdx.x;
    atomicAdd(&hist[seg[i]], 1);
}

// ---------------------------------------------------------------------------
// scan: single WG exclusive prefix over hist[3200] -> offs[3201], cursor copy
// ---------------------------------------------------------------------------
#define SCAN_BPT 13   // 256*13 = 3328 >= 3200
__global__ __launch_bounds__(256) void scan_kernel(
    const int* __restrict__ hist, int* __restrict__ offs, int* __restrict__ cursor)
{
    __shared__ int ps[256];
    const int t = threadIdx.x;
    int local = 0;
    #pragma unroll
    for (int k = 0; k < SCAN_BPT; ++k) {
        int bin = t * SCAN_BPT + k;
        if (bin < NSEG) local += hist[bin];
    }
    ps[t] = local;
    __syncthreads();
    for (int d = 1; d < 256; d <<= 1) {
        int v = (t >= d) ? ps[t - d] : 0;
        __syncthreads();
        ps[t] += v;
        __syncthreads();
    }
    int run = ps[t] - local;   // exclusive start for this thread's range
    #pragma unroll
    for (int k = 0; k < SCAN_BPT; ++k) {
        int bin = t * SCAN_BPT + k;
        if (bin < NSEG) {
            offs[bin] = run;
            cursor[bin] = run;
            run += hist[bin];
        }
    }
    if (t == 255) offs[NSEG] = ps[255];   // = N_SAMPLES
}

__global__ __launch_bounds__(256) void scatter_kernel(
    const int* __restrict__ seg, int* __restrict__ cursor, int* __restrict__ perm)
{
    int i = blockIdx.x * 256 + threadIdx.x;
    int pos = atomicAdd(&cursor[seg[i]], 1);
    perm[pos] = i;
}

// ---------------------------------------------------------------------------
// segsum v6: wave = (segment, 512-col chunk), lane = 8 floats. 8-row batches
// put 16 independent 16B loads in flight before the first use — for the
// common n<=8 segment a wave issues ALL its x loads back-to-back, one wait.
// ---------------------------------------------------------------------------
__global__ __launch_bounds__(256) void segsum_kernel(
    const float* __restrict__ x, const int* __restrict__ perm,
    const int* __restrict__ offs,
    unsigned short* __restrict__ xb, float* __restrict__ sum_bl)
{
    const int tid = threadIdx.x;
    const int w = tid >> 6, lane = tid & 63;
    const int s = blockIdx.y * 4 + w;              // segment, 0..3199
    const int c = blockIdx.x * 512 + lane * 8;     // 8 consecutive floats/lane
    const int beg = offs[s], end = offs[s + 1];

    floatx4 sum0 = {0.f, 0.f, 0.f, 0.f};
    floatx4 sum1 = {0.f, 0.f, 0.f, 0.f};
    for (int base = beg; base < end; base += 64) {
        int p = (base + lane < end) ? perm[base + lane] : 0;
        const int n = min(end - base, 64);
        for (int j0 = 0; j0 < n; j0 += 8) {
            int rr[8];
            floatx4 v0[8], v1[8];
            #pragma unroll
            for (int j = 0; j < 8; ++j) {
                rr[j] = __shfl(p, min(j0 + j, n - 1));   // clamp: dup loads harmless
                const float* px = &x[(size_t)rr[j] * DIM + c];
                v0[j] = *(const floatx4*)px;
                v1[j] = *(const floatx4*)(px + 4);
            }
            #pragma unroll
            for (int j = 0; j < 8; ++j) {
                if (j < n - j0) {
                    sum0 += v0[j];
                    sum1 += v1[j];
                    uint4 o;
                    o.x = pack_bf16x2(v0[j][0], v0[j][1]);
                    o.y = pack_bf16x2(v0[j][2], v0[j][3]);
                    o.z = pack_bf16x2(v1[j][0], v1[j][1]);
                    o.w = pack_bf16x2(v1[j][2], v1[j][3]);
                    *(uint4*)&xb[(size_t)rr[j] * DIM + c] = o;   // 16B/lane
                }
            }
        }
    }
    *(floatx4*)&sum_bl[(size_t)s * DIM + c] = sum0;
    *(floatx4*)&sum_bl[(size_t)s * DIM + c + 4] = sum1;
}

// ---------------------------------------------------------------------------
// meanm (fused batch-total + LOO mean): WG = (batch, 256-col chunk).
// ---------------------------------------------------------------------------
__global__ __launch_bounds__(256) void meanm_kernel(
    const float* __restrict__ sum_bl, const int* __restrict__ offs,
    unsigned short* __restrict__ Mb)
{
    __shared__ float acc[NL][256];   // 100 KB
    const int tid = threadIdx.x;
    const int b = blockIdx.y;
    const int c = blockIdx.x * 256 + tid;

    float tot = 0.f;
    for (int l0 = 0; l0 < NL; l0 += 4) {        // 100 % 4 == 0
        float v[4];
        #pragma unroll
        for (int j = 0; j < 4; ++j)
            v[j] = sum_bl[(size_t)(b * NL + l0 + j) * DIM + c];
        #pragma unroll
        for (int j = 0; j < 4; ++j) { acc[l0 + j][tid] = v[j]; tot += v[j]; }
    }

    const int ob = offs[b * NL];
    const int cb = offs[(b + 1) * NL] - ob;     // batch count
    for (int l = 0; l < NL; ++l) {
        int dc = cb - (offs[b * NL + l + 1] - offs[b * NL + l]);
        float m = (dc > 0) ? (tot - acc[l][tid]) / (float)dc : 0.f;
        Mb[(size_t)(b * NL + l) * DIM + c] = f32_to_bf16(m);
    }
}

// ---------------------------------------------------------------------------
// GEMM: C[M,256] = A[M,K]_bf16 @ B[256,K]_bf16^T  (m97 structure).
// Waves arranged WRxWC over BMxBN; wave subtile (BM/WR)x(BN/WC) = 32x64 in
// both instantiations -> FM=2, FN=4, 8 MFMA/wave-iter.
// KSPLIT>1: blockIdx.z = K-slice, epilogue atomicAdd (C pre-zeroed).
// FUSE: += bias[col] + add[seg[row]*256 + col]
// ---------------------------------------------------------------------------
template<int BM, int BN, int WR, int WC, bool FUSE, int KSPLIT>
__global__ __launch_bounds__(256) void gemm_bt_kernel(
    const unsigned short* __restrict__ A,
    const unsigned short* __restrict__ B,
    float* __restrict__ C,
    const float* __restrict__ bias,
    const float* __restrict__ add,
    const int* __restrict__ seg,
    int K)
{
    constexpr int SM = BM / WR, SN = BN / WC;
    constexpr int FM = SM / 16, FN = SN / 16;
    __shared__ __align__(16) unsigned short ldsA[BM * 32];
    __shared__ __align__(16) unsigned short ldsB[BN * 32];
    const int tid = threadIdx.x;
    const int lane = tid & 63;
    const int wave = tid >> 6;
    const int wr = wave / WC, wc = wave % WC;
    const int quad = lane >> 4, l15 = lane & 15;
    const int m0 = blockIdx.x * BM;
    const int n0 = blockIdx.y * BN;
    const int kpw = K / KSPLIT;
    const int k0 = blockIdx.z * kpw;
    const int srow = lane >> 2, schunk = lane & 3;

    floatx4 acc[FM][FN];
    #pragma unroll
    for (int i = 0; i < FM; ++i)
        #pragma unroll
        for (int j = 0; j < FN; ++j) acc[i][j] = (floatx4){0.f, 0.f, 0.f, 0.f};

    const unsigned short* Abase = A + (size_t)(m0 + srow) * K + schunk * 8;
    const unsigned short* Bbase = B + (size_t)(n0 + srow) * K + schunk * 8;

    for (int kk = k0; kk < k0 + kpw; kk += 32) {
        __syncthreads();
        #pragma unroll
        for (int ch = wave; ch < BM / 16; ch += 4)
            __builtin_amdgcn_global_load_lds(
                (const __attribute__((address_space(1))) void*)(Abase + (size_t)ch * 16 * K + kk),
                (__attribute__((address_space(3))) void*)&ldsA[ch * 16 * 32], 16, 0, 0);
        #pragma unroll
        for (int ch = wave; ch < BN / 16; ch += 4)
            __builtin_amdgcn_global_load_lds(
                (const __attribute__((address_space(1))) void*)(Bbase + (size_t)ch * 16 * K + kk),
                (__attribute__((address_space(3))) void*)&ldsB[ch * 16 * 32], 16, 0, 0);
        __syncthreads();

        bf16x8 af[FM], bfr[FN];
        #pragma unroll
        for (int mi = 0; mi < FM; ++mi)
            af[mi] = *(const bf16x8*)&ldsA[(wr * SM + mi * 16 + l15) * 32 + quad * 8];
        #pragma unroll
        for (int ni = 0; ni < FN; ++ni)
            bfr[ni] = *(const bf16x8*)&ldsB[(wc * SN + ni * 16 + l15) * 32 + quad * 8];
        #pragma unroll
        for (int mi = 0; mi < FM; ++mi)
            #pragma unroll
            for (int ni = 0; ni < FN; ++ni)
                acc[mi][ni] = __builtin_amdgcn_mfma_f32_16x16x32_bf16(
                    af[mi], bfr[ni], acc[mi][ni], 0, 0, 0);
    }

    #pragma unroll
    for (int mi = 0; mi < FM; ++mi) {
        const int rbase = m0 + wr * SM + mi * 16 + quad * 4;
        #pragma unroll
        for (int ni = 0; ni < FN; ++ni) {
            const int col = n0 + wc * SN + ni * 16 + l15;
            float bsum = 0.f;
            if constexpr (FUSE) bsum = bias[col];
            #pragma unroll
            for (int r = 0; r < 4; ++r) {
                const int row = rbase + r;
                float v = acc[mi][ni][r];
                if constexpr (FUSE) v += bsum + add[(size_t)seg[row] * PDIM + col];
                if constexpr (KSPLIT > 1)
                    atomicAdd(&C[(size_t)row * PDIM + col], v);
                else
                    C[(size_t)row * PDIM + col] = v;
            }
        }
    }
}

// ---------------------------------------------------------------------------
extern "C" void kernel_launch(void* const* d_in, const int* in_sizes, int n_in,
                              void* d_out, int out_size, void* d_ws, size_t ws_size,
                              hipStream_t stream)
{
    const float* x      = (const float*)d_in[0];
    const int*   label  = (const int*)d_in[1];
    const int*   lbatch = (const int*)d_in[2];
    const float* W1w    = (const float*)d_in[3];
    const float* W1b    = (const float*)d_in[4];
    const float* W2w    = (const float*)d_in[5];
    const float* W2b    = (const float*)d_in[6];
    float* out = (float*)d_out;

    char* ws = (char*)d_ws;
    size_t off = 0;
    auto alloc = [&](size_t bytes) {
        void* p = ws + off;
        off = (off + bytes + 255) & ~(size_t)255;
        return p;
    };
    unsigned short* xb   = (unsigned short*)alloc((size_t)N_SAMPLES * DIM * 2); // 67 MB
    unsigned short* Mb   = (unsigned short*)alloc((size_t)NSEG * DIM * 2);      // 13 MB
    unsigned short* W1bf = (unsigned short*)alloc((size_t)PDIM * DIM * 2);
    unsigned short* W2bf = (unsigned short*)alloc((size_t)PDIM * DIM * 2);
    float* MW2    = (float*)alloc((size_t)NSEG * PDIM * 4);                     // 3.3 MB
    float* sum_bl = (float*)alloc((size_t)NSEG * DIM * 4);                      // 26 MB
    float* bias   = (float*)alloc(PDIM * 4);
    int*   seg    = (int*)alloc(N_SAMPLES * 4);
    int*   perm   = (int*)alloc(N_SAMPLES * 4);
    int*   hist   = (int*)alloc(NSEG * 4);
    int*   offs   = (int*)alloc((NSEG + 1) * 4);
    int*   cursor = (int*)alloc(NSEG * 4);

    prep_kernel<<<PDIM * DIM / 256, 256, 0, stream>>>(
        W1w, W1b, W2w, W2b, label, lbatch, W1bf, W2bf, bias, seg, hist, MW2);

    hist_kernel<<<N_SAMPLES / 256, 256, 0, stream>>>(seg, hist);
    scan_kernel<<<1, 256, 0, stream>>>(hist, offs, cursor);
    scatter_kernel<<<N_SAMPLES / 256, 256, 0, stream>>>(seg, cursor, perm);

    segsum_kernel<<<dim3(DIM / 512, NSEG / 4), 256, 0, stream>>>(
        x, perm, offs, xb, sum_bl);

    meanm_kernel<<<dim3(DIM / 256, NB), 256, 0, stream>>>(sum_bl, offs, Mb);

    // MW2[3200,256] = M @ W2^T : 32x256 tile, split-K=2, atomic f32 epilogue
    gemm_bt_kernel<32, 256, 1, 4, false, 2>
        <<<dim3(NSEG / 32, 1, 2), 256, 0, stream>>>(
        Mb, W2bf, MW2, nullptr, nullptr, nullptr, DIM);

    // out[16384,256] = x @ W1^T + bias + MW2[seg] : 64x128, 512 WGs = 2/CU
    gemm_bt_kernel<64, 128, 2, 2, true, 1>
        <<<dim3(N_SAMPLES / 64, PDIM / 128), 256, 0, stream>>>(
        xb, W1bf, out, bias, MW2, seg, DIM);
}